// Round 1
// baseline (160.282 us; speedup 1.0000x reference)
//
#include <hip/hip_runtime.h>
#include <hip/hip_bf16.h>

// Problem constants (from reference setup_inputs):
//   B=256 (batch / rows+cols of simMax), P=64 (proposals), D=1024 (feature dim)
//   MARGIN = 0.1
constexpr int NB = 256;
constexpr int NP = 64;
constexpr int ND = 1024;
constexpr int KT = 16;   // K-chunk staged in LDS per iteration
constexpr float MARGIN = 0.1f;

// ---------------------------------------------------------------------------
// Kernel 1: simMax[i][c] = max_p  sum_d imFtr[i][p][d] * disFtr[c][d]
// grid = 256 (one block per image i), block = 256 threads.
// Per-thread 8x8 register tile: p in [ty*8, ty*8+8), c in {tx*4+u, 128+tx*4+u}.
// LDS layouts are k-major so inner-loop b128 reads are lane-consecutive.
// ---------------------------------------------------------------------------
__global__ __launch_bounds__(256) void simmax_kernel(
    const float* __restrict__ imFtr, const float* __restrict__ disFtr,
    float* __restrict__ simMax) {
  const int i  = blockIdx.x;
  const int t  = threadIdx.x;
  const int tx = t & 31;   // c-group
  const int ty = t >> 5;   // p-group (0..7)

  __shared__ float As[KT][NP];   // 4 KB   As[k][p]
  __shared__ float Bs[KT][NB];   // 16 KB  Bs[k][c]
  __shared__ float Red[8][NB];   // 8 KB   cross-ty max reduce

  float acc[8][8];
#pragma unroll
  for (int a = 0; a < 8; ++a)
#pragma unroll
    for (int b = 0; b < 8; ++b) acc[a][b] = 0.0f;

  const float* Ai = imFtr + (size_t)i * NP * ND;
  const int p_a = t & 63;   // A staging: thread loads float4 of row p_a
  const int kq  = t >> 6;   // ... at k-offset kq*4 (waves cover kq 0..3)

  for (int k0 = 0; k0 < ND; k0 += KT) {
    __syncthreads();  // previous chunk's LDS reads must be done before overwrite
    // --- stage A chunk: 64 p x 16 k ---
    float4 av = *reinterpret_cast<const float4*>(Ai + (size_t)p_a * ND + k0 + kq * 4);
    As[kq * 4 + 0][p_a] = av.x;
    As[kq * 4 + 1][p_a] = av.y;
    As[kq * 4 + 2][p_a] = av.z;
    As[kq * 4 + 3][p_a] = av.w;
    // --- stage B chunk: 256 c x 16 k (disFtr row t) ---
#pragma unroll
    for (int q = 0; q < 4; ++q) {
      float4 bv = *reinterpret_cast<const float4*>(disFtr + (size_t)t * ND + k0 + q * 4);
      Bs[q * 4 + 0][t] = bv.x;
      Bs[q * 4 + 1][t] = bv.y;
      Bs[q * 4 + 2][t] = bv.z;
      Bs[q * 4 + 3][t] = bv.w;
    }
    __syncthreads();
    // --- inner product over the staged K chunk ---
#pragma unroll
    for (int kk = 0; kk < KT; ++kk) {
      float a_[8], b_[8];
      *reinterpret_cast<float4*>(&a_[0]) =
          *reinterpret_cast<const float4*>(&As[kk][ty * 8]);
      *reinterpret_cast<float4*>(&a_[4]) =
          *reinterpret_cast<const float4*>(&As[kk][ty * 8 + 4]);
      *reinterpret_cast<float4*>(&b_[0]) =
          *reinterpret_cast<const float4*>(&Bs[kk][tx * 4]);
      *reinterpret_cast<float4*>(&b_[4]) =
          *reinterpret_cast<const float4*>(&Bs[kk][128 + tx * 4]);
#pragma unroll
      for (int a = 0; a < 8; ++a)
#pragma unroll
        for (int b = 0; b < 8; ++b) acc[a][b] = fmaf(a_[a], b_[b], acc[a][b]);
    }
  }

  // per-thread max over the 8 p's
  float m[8];
#pragma unroll
  for (int b = 0; b < 8; ++b) {
    float v = acc[0][b];
#pragma unroll
    for (int a = 1; a < 8; ++a) v = fmaxf(v, acc[a][b]);
    m[b] = v;
  }
  // cross-ty max reduce via LDS (Red is a distinct buffer; only one sync needed)
#pragma unroll
  for (int b = 0; b < 4; ++b) Red[ty][tx * 4 + b] = m[b];
#pragma unroll
  for (int b = 0; b < 4; ++b) Red[ty][128 + tx * 4 + b] = m[4 + b];
  __syncthreads();
  float v = Red[0][t];
#pragma unroll
  for (int r = 1; r < 8; ++r) v = fmaxf(v, Red[r][t]);
  simMax[(size_t)i * NB + t] = v;
}

// ---------------------------------------------------------------------------
// Kernel 2: per-row partial sums of {mask count, loss_it, loss_ti}.
// grid = 256 (row i), block = 256 (col j). Deterministic (no atomics).
// partial layout: [row][3]
// ---------------------------------------------------------------------------
__global__ __launch_bounds__(256) void loss_kernel(
    const float* __restrict__ simMax, const int* __restrict__ lbl,
    float* __restrict__ partial) {
  const int i = blockIdx.x;
  const int j = threadIdx.x;
  __shared__ float posi_sh;
  __shared__ float red[3][4];

  float s = simMax[(size_t)i * NB + j];
  if (j == i) posi_sh = s;
  __syncthreads();
  const float posi = posi_sh;
  const float posj = simMax[(size_t)j * NB + j];

  const float msk = (lbl[i] != lbl[j]) ? 1.0f : 0.0f;  // diagonal auto-excluded
  float c  = msk;
  float l1 = msk * fmaxf(s - posi + MARGIN, 0.0f);
  float l2 = msk * fmaxf(s - posj + MARGIN, 0.0f);
#pragma unroll
  for (int o = 32; o > 0; o >>= 1) {
    c  += __shfl_down(c, o);
    l1 += __shfl_down(l1, o);
    l2 += __shfl_down(l2, o);
  }
  const int w = j >> 6;
  if ((j & 63) == 0) { red[0][w] = c; red[1][w] = l1; red[2][w] = l2; }
  __syncthreads();
  if (j == 0) {
    partial[i * 3 + 0] = red[0][0] + red[0][1] + red[0][2] + red[0][3];
    partial[i * 3 + 1] = red[1][0] + red[1][1] + red[1][2] + red[1][3];
    partial[i * 3 + 2] = red[2][0] + red[2][1] + red[2][2] + red[2][3];
  }
}

// ---------------------------------------------------------------------------
// Kernel 3: final deterministic reduction over 256 row-partials -> loss scalar
// 1 block, 256 threads.
// ---------------------------------------------------------------------------
__global__ __launch_bounds__(256) void finalize_kernel(
    const float* __restrict__ partial, float* __restrict__ out) {
  const int t = threadIdx.x;
  __shared__ float red[3][4];
  float c  = partial[t * 3 + 0];
  float l1 = partial[t * 3 + 1];
  float l2 = partial[t * 3 + 2];
#pragma unroll
  for (int o = 32; o > 0; o >>= 1) {
    c  += __shfl_down(c, o);
    l1 += __shfl_down(l1, o);
    l2 += __shfl_down(l2, o);
  }
  const int w = t >> 6;
  if ((t & 63) == 0) { red[0][w] = c; red[1][w] = l1; red[2][w] = l2; }
  __syncthreads();
  if (t == 0) {
    float cs  = red[0][0] + red[0][1] + red[0][2] + red[0][3];
    float l1s = red[1][0] + red[1][1] + red[1][2] + red[1][3];
    float l2s = red[2][0] + red[2][1] + red[2][2] + red[2][3];
    float loss = l1s / cs;                      // reference divides unconditionally
    loss += (cs > 0.0f) ? (l2s / cs) : 0.0f;    // guarded second term, as in ref
    out[0] = loss;
  }
}

extern "C" void kernel_launch(void* const* d_in, const int* in_sizes, int n_in,
                              void* d_out, int out_size, void* d_ws, size_t ws_size,
                              hipStream_t stream) {
  (void)in_sizes; (void)n_in; (void)out_size; (void)ws_size;
  const float* imFtr  = (const float*)d_in[0];
  const float* disFtr = (const float*)d_in[1];
  const int*   lbl    = (const int*)d_in[2];
  float* out = (float*)d_out;

  float* simMax  = (float*)d_ws;                               // 256*256*4 = 256 KB
  float* partial = (float*)((char*)d_ws + (size_t)NB * NB * 4); // 256*3*4 = 3 KB

  simmax_kernel<<<dim3(NB), dim3(256), 0, stream>>>(imFtr, disFtr, simMax);
  loss_kernel<<<dim3(NB), dim3(256), 0, stream>>>(simMax, lbl, partial);
  finalize_kernel<<<dim3(1), dim3(256), 0, stream>>>(partial, out);
}

// Round 2
// 41.104 us; speedup vs baseline: 3.8994x; 3.8994x over previous
//
#include <hip/hip_runtime.h>

// Problem constants: B=256, P=64, D=1024, MARGIN=0.1
constexpr int NB = 256;
constexpr int NP = 64;
constexpr int ND = 1024;
constexpr float MARGIN = 0.1f;

typedef __attribute__((ext_vector_type(8))) short short8;  // 8 bf16 (4 VGPRs)
typedef __attribute__((ext_vector_type(4))) float f32x4;   // MFMA accumulator

// fp32 -> bf16 round-to-nearest-even (inputs are finite gaussians; no NaN path)
static __device__ inline unsigned short f2bf(float f) {
  unsigned u = __builtin_bit_cast(unsigned, f);
  u += 0x7fffu + ((u >> 16) & 1u);
  return (unsigned short)(u >> 16);
}

static __device__ inline short8 cvt8(float4 a, float4 b) {
  short8 r;
  r[0] = (short)f2bf(a.x); r[1] = (short)f2bf(a.y);
  r[2] = (short)f2bf(a.z); r[3] = (short)f2bf(a.w);
  r[4] = (short)f2bf(b.x); r[5] = (short)f2bf(b.y);
  r[6] = (short)f2bf(b.z); r[7] = (short)f2bf(b.w);
  return r;
}

// ---------------------------------------------------------------------------
// simMax[i][c] = max_p sum_d imFtr[i][p][d]*disFtr[c][d]   via bf16 MFMA.
// grid=256 (one block per i), 512 threads = 8 waves.
// Wave w owns c in [w*32, w*32+32) (2 c-tiles of 16), all 64 p (4 p-tiles).
// A (imFtr slice) staged per 64-k chunk in LDS (bf16, XOR-swizzled 16B slots);
// B (disFtr) direct global->reg, each element read once per block (L2-hot).
// MFMA: mfma_f32_16x16x32_bf16; A-frag lane l = A[l&15][(l>>4)*8+j],
// B-frag identical pattern on disFtr rows (B^T input), D: row=(l>>4)*4+r, col=l&15.
// ---------------------------------------------------------------------------
__global__ __launch_bounds__(512) void simmax_kernel(
    const float* __restrict__ imFtr, const float* __restrict__ disFtr,
    float* __restrict__ simMax) {
  const int i  = blockIdx.x;
  const int t  = threadIdx.x;
  const int w  = t >> 6;   // wave 0..7
  const int l  = t & 63;
  const int lr = l & 15;   // tile row (A) / tile col (B,D)
  const int lk = l >> 4;   // k-group 0..3

  // A chunk: 64 rows x 64 k, bf16. Element [row][k] lives at
  // [row][ ((k/8) ^ (row&7))*8 + (k%8) ]  -> conflict-free b128 reads/writes.
  __shared__ short Asl[NP][64];  // 8 KB

  f32x4 acc[4][2];
#pragma unroll
  for (int pt = 0; pt < 4; ++pt)
#pragma unroll
    for (int ct = 0; ct < 2; ++ct)
#pragma unroll
      for (int r = 0; r < 4; ++r) acc[pt][ct][r] = 0.0f;

  // --- A staging assignment: thread t loads row ar, k-slot aks (8 fp32 = 32B)
  const int ar  = t >> 3;
  const int aks = t & 7;
  const float* ap = imFtr + (size_t)i * NP * ND + (size_t)ar * ND + aks * 8;
  const int wslot = ((aks ^ (ar & 7)) * 8);
  float4 av0 = *reinterpret_cast<const float4*>(ap);
  float4 av1 = *reinterpret_cast<const float4*>(ap + 4);

  // --- B pointers: wave-local c rows, lane-local k offset
  const float* bp0 = disFtr + (size_t)(w * 32 + lr) * ND + lk * 8;
  const float* bp1 = disFtr + (size_t)(w * 32 + 16 + lr) * ND + lk * 8;

  for (int kc = 0; kc < 16; ++kc) {
    const int kbase = kc * 64;
    // Issue ALL B loads for this chunk before the barriers (overlap).
    float4 bld[2][2][2];  // [ks][ct][half]
#pragma unroll
    for (int ks = 0; ks < 2; ++ks) {
      const int ko = kbase + ks * 32;
      bld[ks][0][0] = *reinterpret_cast<const float4*>(bp0 + ko);
      bld[ks][0][1] = *reinterpret_cast<const float4*>(bp0 + ko + 4);
      bld[ks][1][0] = *reinterpret_cast<const float4*>(bp1 + ko);
      bld[ks][1][1] = *reinterpret_cast<const float4*>(bp1 + ko + 4);
    }
    __syncthreads();  // previous chunk's LDS reads complete
    *reinterpret_cast<short8*>(&Asl[ar][wslot]) = cvt8(av0, av1);
    if (kc < 15) {  // prefetch next A chunk (lands during this chunk's MFMAs)
      const float* apn = ap + (kc + 1) * 64;
      av0 = *reinterpret_cast<const float4*>(apn);
      av1 = *reinterpret_cast<const float4*>(apn + 4);
    }
    __syncthreads();  // A chunk staged

#pragma unroll
    for (int ks = 0; ks < 2; ++ks) {
      short8 bfr0 = cvt8(bld[ks][0][0], bld[ks][0][1]);
      short8 bfr1 = cvt8(bld[ks][1][0], bld[ks][1][1]);
#pragma unroll
      for (int pt = 0; pt < 4; ++pt) {
        const int row  = pt * 16 + lr;
        const int slot = (((ks * 4 + lk) ^ (row & 7)) * 8);
        short8 afr = *reinterpret_cast<const short8*>(&Asl[row][slot]);
        acc[pt][0] = __builtin_amdgcn_mfma_f32_16x16x32_bf16(afr, bfr0, acc[pt][0], 0, 0, 0);
        acc[pt][1] = __builtin_amdgcn_mfma_f32_16x16x32_bf16(afr, bfr1, acc[pt][1], 0, 0, 0);
      }
    }
  }

  // max over p: per-lane 16 values (4 pt x 4 r), then cross-lane over k-groups
#pragma unroll
  for (int ct = 0; ct < 2; ++ct) {
    float m = acc[0][ct][0];
#pragma unroll
    for (int pt = 0; pt < 4; ++pt)
#pragma unroll
      for (int r = 0; r < 4; ++r) m = fmaxf(m, acc[pt][ct][r]);
    m = fmaxf(m, __shfl_xor(m, 16));
    m = fmaxf(m, __shfl_xor(m, 32));
    if (l < 16) simMax[(size_t)i * NB + w * 32 + ct * 16 + l] = m;
  }
}

// ---------------------------------------------------------------------------
// Kernel 2: per-row partial sums of {mask count, loss_it, loss_ti}.
// ---------------------------------------------------------------------------
__global__ __launch_bounds__(256) void loss_kernel(
    const float* __restrict__ simMax, const int* __restrict__ lbl,
    float* __restrict__ partial) {
  const int i = blockIdx.x;
  const int j = threadIdx.x;
  __shared__ float posi_sh;
  __shared__ float red[3][4];

  float s = simMax[(size_t)i * NB + j];
  if (j == i) posi_sh = s;
  __syncthreads();
  const float posi = posi_sh;
  const float posj = simMax[(size_t)j * NB + j];

  const float msk = (lbl[i] != lbl[j]) ? 1.0f : 0.0f;
  float c  = msk;
  float l1 = msk * fmaxf(s - posi + MARGIN, 0.0f);
  float l2 = msk * fmaxf(s - posj + MARGIN, 0.0f);
#pragma unroll
  for (int o = 32; o > 0; o >>= 1) {
    c  += __shfl_down(c, o);
    l1 += __shfl_down(l1, o);
    l2 += __shfl_down(l2, o);
  }
  const int w = j >> 6;
  if ((j & 63) == 0) { red[0][w] = c; red[1][w] = l1; red[2][w] = l2; }
  __syncthreads();
  if (j == 0) {
    partial[i * 3 + 0] = red[0][0] + red[0][1] + red[0][2] + red[0][3];
    partial[i * 3 + 1] = red[1][0] + red[1][1] + red[1][2] + red[1][3];
    partial[i * 3 + 2] = red[2][0] + red[2][1] + red[2][2] + red[2][3];
  }
}

// ---------------------------------------------------------------------------
// Kernel 3: final reduction over 256 row-partials -> loss scalar.
// ---------------------------------------------------------------------------
__global__ __launch_bounds__(256) void finalize_kernel(
    const float* __restrict__ partial, float* __restrict__ out) {
  const int t = threadIdx.x;
  __shared__ float red[3][4];
  float c  = partial[t * 3 + 0];
  float l1 = partial[t * 3 + 1];
  float l2 = partial[t * 3 + 2];
#pragma unroll
  for (int o = 32; o > 0; o >>= 1) {
    c  += __shfl_down(c, o);
    l1 += __shfl_down(l1, o);
    l2 += __shfl_down(l2, o);
  }
  const int w = t >> 6;
  if ((t & 63) == 0) { red[0][w] = c; red[1][w] = l1; red[2][w] = l2; }
  __syncthreads();
  if (t == 0) {
    float cs  = red[0][0] + red[0][1] + red[0][2] + red[0][3];
    float l1s = red[1][0] + red[1][1] + red[1][2] + red[1][3];
    float l2s = red[2][0] + red[2][1] + red[2][2] + red[2][3];
    float loss = l1s / cs;                   // reference divides unconditionally
    loss += (cs > 0.0f) ? (l2s / cs) : 0.0f; // guarded second term, as in ref
    out[0] = loss;
  }
}

extern "C" void kernel_launch(void* const* d_in, const int* in_sizes, int n_in,
                              void* d_out, int out_size, void* d_ws, size_t ws_size,
                              hipStream_t stream) {
  (void)in_sizes; (void)n_in; (void)out_size; (void)ws_size;
  const float* imFtr  = (const float*)d_in[0];
  const float* disFtr = (const float*)d_in[1];
  const int*   lbl    = (const int*)d_in[2];
  float* out = (float*)d_out;

  float* simMax  = (float*)d_ws;                                // 256 KB
  float* partial = (float*)((char*)d_ws + (size_t)NB * NB * 4); // 3 KB

  simmax_kernel<<<dim3(NB), dim3(512), 0, stream>>>(imFtr, disFtr, simMax);
  loss_kernel<<<dim3(NB), dim3(256), 0, stream>>>(simMax, lbl, partial);
  finalize_kernel<<<dim3(1), dim3(256), 0, stream>>>(partial, out);
}